// Round 4
// baseline (138.429 us; speedup 1.0000x reference)
//
#include <hip/hip_runtime.h>

#define POOL 7
#define NUM_ROIS 300
#define FH 200
#define FW 200
#define FC 512
#define FEAT_F4 (FH * FW * FC / 4)   // 5,120,000 float4s

typedef float f4 __attribute__((ext_vector_type(4)));

// Pass 1: sequential raster read of the whole feature map at streaming BW.
// Warms the 256 MB Infinity Cache (82 MB map fits easily) so the gather
// kernel's scattered reads hit L3 instead of random-order HBM.
// Block sums go to d_ws purely to defeat dead-code elimination.
__global__ __launch_bounds__(256) void warm_l3_kernel(
    const f4* __restrict__ feat4, float* __restrict__ ws)
{
    f4 acc = {0.f, 0.f, 0.f, 0.f};
    const int stride = gridDim.x * 256;
    for (int i = blockIdx.x * 256 + threadIdx.x; i < FEAT_F4; i += stride)
        acc += feat4[i];
    float s = acc.x + acc.y + acc.z + acc.w;
    if (threadIdx.x == 0) ws[blockIdx.x] = s;   // side effect; ws re-poisoned each iter anyway
}

// Pass 2: one block per (roi, py, px) cell. 128 threads x f4 = 512 channels.
__global__ __launch_bounds__(128) void roi_pool_kernel(
    const float* __restrict__ feat,   // (FH, FW, FC) fp32, NHWC
    const int*   __restrict__ rois,   // (NUM_ROIS, 4) int32: x0,y0,w,h
    float*       __restrict__ out)    // (NUM_ROIS, POOL, POOL, FC) fp32
{
    const int cell = blockIdx.x;                // 0 .. NUM_ROIS*49-1
    const int r    = cell / (POOL * POOL);
    const int pp   = cell - r * (POOL * POOL);
    const int py   = pp / POOL;
    const int px   = pp - py * POOL;

    const int x0 = rois[4 * r + 0];
    const int y0 = rois[4 * r + 1];
    const int w  = rois[4 * r + 2];
    const int h  = rois[4 * r + 3];

    // Match reference arithmetic: sy = py*(h/7), sx = px*(w/7) in fp32.
    const float sy = (float)py * ((float)h / 7.0f);
    const float sx = (float)px * ((float)w / 7.0f);
    const int y_lo = (int)floorf(sy);
    const int x_lo = (int)floorf(sx);
    const int y_hi = min(y_lo + 1, h - 1);
    const int x_hi = min(x_lo + 1, w - 1);
    const float fy = sy - (float)y_lo;
    const float fx = sx - (float)x_lo;

    const float w00 = (1.0f - fy) * (1.0f - fx);
    const float w01 = (1.0f - fy) * fx;
    const float w10 = fy * (1.0f - fx);
    const float w11 = fy * fx;

    const size_t row_lo = (size_t)(y0 + y_lo) * FW;
    const size_t row_hi = (size_t)(y0 + y_hi) * FW;
    const f4* __restrict__ f00 = (const f4*)(feat + (row_lo + (x0 + x_lo)) * FC);
    const f4* __restrict__ f01 = (const f4*)(feat + (row_lo + (x0 + x_hi)) * FC);
    const f4* __restrict__ f10 = (const f4*)(feat + (row_hi + (x0 + x_lo)) * FC);
    const f4* __restrict__ f11 = (const f4*)(feat + (row_hi + (x0 + x_hi)) * FC);
    f4* __restrict__ o = (f4*)(out + (size_t)cell * FC);

    const int t = threadIdx.x;                  // 0..127, one f4 each
    const f4 v00 = f00[t];
    const f4 v01 = f01[t];
    const f4 v10 = f10[t];
    const f4 v11 = f11[t];

    const f4 res = v00 * w00 + v01 * w01 + v10 * w10 + v11 * w11;
    // Write-once stream: non-temporal, don't evict feat from L2.
    __builtin_nontemporal_store(res, &o[t]);
}

extern "C" void kernel_launch(void* const* d_in, const int* in_sizes, int n_in,
                              void* d_out, int out_size, void* d_ws, size_t ws_size,
                              hipStream_t stream) {
    const float* feat = (const float*)d_in[0];  // (1,200,200,512) fp32
    const int*   rois = (const int*)d_in[1];    // (1,300,4) int32
    float*       out  = (float*)d_out;          // (1,300,7,7,512) fp32

    warm_l3_kernel<<<2048, 256, 0, stream>>>((const f4*)feat, (float*)d_ws);

    const int n_cells = NUM_ROIS * POOL * POOL; // 14700
    roi_pool_kernel<<<n_cells, 128, 0, stream>>>(feat, rois, out);
}